// Round 6
// baseline (208.435 us; speedup 1.0000x reference)
//
#include <hip/hip_runtime.h>
#include <math.h>

#define GSZ 52
#define NA 3
#define NCLS 80
#define CH 85                    // 5 + NCLS
#define NCA (GSZ*GSZ*NA)         // 8112 cell-anchors per batch
#define MAXGT 64
#define RPB 32                   // records per scan block
#define FPT (RPB*CH)             // 2720 floats per staged tensor chunk
#define F4PT (FPT/4)             // 680 float4
#define MCHUNK 32                // noobj units per batch: 32 x 256 = 8192 >= 8112
#define CLSU 16                  // cls units per batch: 16 x 4 waves = 64 slots

// fast softplus: max(x,0) + log(1+exp(-|x|)) with HW-approx exp/log.
__device__ __forceinline__ float softplus_fast(float x) {
    return fmaxf(x, 0.0f) + __logf(1.0f + __expf(-fabsf(x)));
}

__global__ void k_init(int* cnt, int B) {
    if (threadIdx.x < B) cnt[threadIdx.x] = 0;
}

// Stream-stage scan: read BOTH tensors fully as coalesced float4 streams
// (request slots carry full lines -> stream BW, not the ~0.9 TB/s scattered-
// sector regime). Key fix vs the old k_tp: BATCHED issue — all of a thread's
// global loads go to registers back-to-back (one vmcnt batch), THEN all LDS
// stores. 64-96B in flight per thread instead of 16B loop-carried.
__global__ __launch_bounds__(256) void k_scan(
    const float* __restrict__ tg, const float* __restrict__ pr,
    const float* __restrict__ anchors, int* cnt,
    float4* __restrict__ gtbox, int2* __restrict__ gtinfo,
    float4* __restrict__ boxdec, float* __restrict__ confdec) {
    __shared__ float sT[FPT];
    __shared__ float sP[FPT];
    int tid = threadIdx.x;
    size_t rec0 = (size_t)blockIdx.x * RPB;

    {
        const float4* srcT = (const float4*)(tg + rec0 * CH);
        const float4* srcP = (const float4*)(pr + rec0 * CH);
        float4* dT = (float4*)sT;
        float4* dP = (float4*)sP;
        // 680 float4 per tensor, 256 threads: indices tid, tid+256, tid+512(<680)
        bool has3 = (tid < F4PT - 512);          // tid < 168
        float4 a0 = srcT[tid];
        float4 b0 = srcP[tid];
        float4 a1 = srcT[tid + 256];
        float4 b1 = srcP[tid + 256];
        float4 a2 = make_float4(0.f, 0.f, 0.f, 0.f);
        float4 b2 = a2;
        if (has3) {
            a2 = srcT[tid + 512];
            b2 = srcP[tid + 512];
        }
        dT[tid]       = a0;  dP[tid]       = b0;
        dT[tid + 256] = a1;  dP[tid + 256] = b1;
        if (has3) {
            dT[tid + 512] = a2;
            dP[tid + 512] = b2;
        }
    }
    __syncthreads();

    if (tid < RPB) {
        // GT extraction from staged targets (class scan from LDS — no
        // scattered global re-read on the rare path).
        const float* r = sT + tid * CH;          // stride 85: gcd(85,32)=1, conflict-free
        float conf = r[4];
        if (conf > 0.0f) {
            size_t glob = rec0 + tid;
            int b    = (int)(glob / NCA);
            int nloc = (int)(glob - (size_t)b * NCA);
            int cid = 0;
#pragma unroll 16
            for (int c = 0; c < NCLS; c++) if (r[5 + c] > 0.5f) cid = c;
            int pos = atomicAdd(cnt + b, 1);
            if (pos < MAXGT) {
                gtbox[b * MAXGT + pos]  = make_float4(r[0], r[1], r[2], r[3]);
                gtinfo[b * MAXGT + pos] = make_int2(nloc, cid);
            }
        }
    } else if (tid >= 64 && tid < 64 + RPB) {
        // box decode from staged preds
        int t = tid - 64;
        const float* r = sP + t * CH;
        size_t glob = rec0 + t;
        int b    = (int)(glob / NCA);
        int nloc = (int)(glob - (size_t)b * NCA);
        int a    = nloc % NA;
        int cell = nloc / NA;
        int gi = cell / GSZ, gj = cell % GSZ;
        float sx = __builtin_amdgcn_rcpf(1.0f + __expf(-r[0]));
        float sy = __builtin_amdgcn_rcpf(1.0f + __expf(-r[1]));
        float ew = __expf(r[2]), eh = __expf(r[3]);
        float aw = anchors[2 * a], ah = anchors[2 * a + 1];
        boxdec[glob]  = make_float4((sx + (float)gj) * 8.0f,
                                    (sy + (float)gi) * 8.0f,
                                    ew * aw, eh * ah);
        confdec[glob] = r[4];
    }
}

// Fused noobj + cls kernel (proven structure, no device-scope sync).
__global__ __launch_bounds__(256) void k_nc(
    const float* __restrict__ pr,
    const float* __restrict__ anchors,
    const int* __restrict__ cnt,
    const float4* __restrict__ gtbox,
    const int2* __restrict__ gtinfo,
    const float4* __restrict__ boxdec,
    const float* __restrict__ confdec,
    float* __restrict__ partial,
    float4* __restrict__ cls4) {
    __shared__ float4 sbox[MAXGT];
    __shared__ int    sidx[MAXGT];
    __shared__ float  swsum[4];

    int b   = blockIdx.y;
    int tid = threadIdx.x;

    if (blockIdx.x < MCHUNK) {
        int n = blockIdx.x * 256 + tid;
        int m = min(cnt[b], MAXGT);
        if (tid < m) {
            sbox[tid] = gtbox[b * MAXGT + tid];
            sidx[tid] = gtinfo[b * MAXGT + tid].x;
        }
        __syncthreads();

        float v = 0.0f;
        if (n < NCA) {
            size_t rec = (size_t)b * NCA + n;
            float4 pb = boxdec[rec];
            float  pc = confdec[rec];
            float px0 = pb.x - pb.z * 0.5f, px1 = pb.x + pb.z * 0.5f;
            float py0 = pb.y - pb.w * 0.5f, py1 = pb.y + pb.w * 0.5f;
            float areap = pb.z * pb.w;

            float best = 0.0f;
            bool isobj = false;
            for (int k = 0; k < m; k++) {
                float4 g = sbox[k];
                isobj |= (sidx[k] == n);
                float ix = fminf(px1, g.x + g.z * 0.5f) - fmaxf(px0, g.x - g.z * 0.5f);
                float iy = fminf(py1, g.y + g.w * 0.5f) - fmaxf(py0, g.y - g.w * 0.5f);
                float inter = fmaxf(ix, 0.0f) * fmaxf(iy, 0.0f);
                float u = areap + g.z * g.w - inter + 1e-9f;
                best = fmaxf(best, inter * __builtin_amdgcn_rcpf(u));
            }
            if (!isobj && best < 0.6f) v = softplus_fast(pc);
        }

        int lane = tid & 63;
        int wv   = tid >> 6;
        for (int off = 32; off > 0; off >>= 1) v += __shfl_down(v, off);
        if (lane == 0) swsum[wv] = v;
        __syncthreads();
        if (tid == 0)
            partial[b * MCHUNK + blockIdx.x] = swsum[0] + swsum[1] + swsum[2] + swsum[3];
    } else {
        int wv   = tid >> 6;
        int lane = tid & 63;
        int slot = b * MAXGT + (blockIdx.x - MCHUNK) * 4 + wv;
        int k    = slot & (MAXGT - 1);

        float4 resv = make_float4(0.f, 0.f, 0.f, 0.f);
        int m = min(cnt[b], MAXGT);
        if (k < m) {
            float4 g  = gtbox[slot];
            int2 info = gtinfo[slot];
            int n = info.x, cid = info.y;
            size_t rec = (size_t)b * NCA + n;
            const float* cl = pr + rec * CH + 5;

            float x0 = cl[lane];
            float cls = softplus_fast(x0) - (lane == cid ? x0 : 0.0f);
            if (lane < NCLS - 64) {
                float x1 = cl[64 + lane];
                cls += softplus_fast(x1) - ((64 + lane) == cid ? x1 : 0.0f);
            }
            for (int off = 32; off > 0; off >>= 1) cls += __shfl_down(cls, off);

            if (lane == 0) {
                float4 pb = boxdec[rec];
                float  pc = confdec[rec];
                int a    = n % NA;
                int cell = n / NA;
                int gi = cell / GSZ, gj = cell % GSZ;
                float aw = anchors[2 * a], ah = anchors[2 * a + 1];

                float scale = 2.0f - (g.z * (1.0f / 416.0f)) * (g.w * (1.0f / 416.0f));
                float dx = (pb.x * 0.125f - (float)gj) - (g.x * 0.125f - (float)gj);
                float dy = (pb.y * 0.125f - (float)gi) - (g.y * 0.125f - (float)gi);
                float txty = (dx * dx + dy * dy) * scale;

                float rw = __builtin_amdgcn_rcpf(aw), rh = __builtin_amdgcn_rcpf(ah);
                float pwr = fminf(fmaxf(pb.z * rw, 1e-9f), 1e9f);
                float phr = fminf(fmaxf(pb.w * rh, 1e-9f), 1e9f);
                float twr = fminf(fmaxf(g.z  * rw, 1e-9f), 1e9f);
                float thr = fminf(fmaxf(g.w  * rh, 1e-9f), 1e9f);
                float dw = __logf(pwr) - __logf(twr);
                float dh = __logf(phr) - __logf(thr);
                float twth = (dw * dw + dh * dh) * scale;

                float obj = softplus_fast(pc) - pc;
                resv = make_float4(txty, twth, obj, cls);
            }
        }
        if (lane == 0) cls4[slot] = resv;
    }
}

__global__ void k_final(const float* __restrict__ partial, int np,
                        const float4* __restrict__ cls4, int ns,
                        int B, float* __restrict__ out) {
    __shared__ double sred[4 * 5];
    int tid = threadIdx.x;
    double acc[5] = {0, 0, 0, 0, 0};   // txty, twth, noobj, obj, cls
    for (int i = tid; i < np; i += 256) acc[2] += (double)partial[i];
    for (int i = tid; i < ns; i += 256) {
        float4 v = cls4[i];
        acc[0] += (double)v.x; acc[1] += (double)v.y;
        acc[3] += (double)v.z; acc[4] += (double)v.w;
    }
    int lane = tid & 63;
    int wv   = tid >> 6;
#pragma unroll
    for (int i = 0; i < 5; i++) {
        double v = acc[i];
        for (int off = 32; off > 0; off >>= 1) v += __shfl_down(v, off);
        if (lane == 0) sred[wv * 5 + i] = v;
    }
    __syncthreads();
    if (tid == 0) {
        double tot = 0.0;
#pragma unroll
        for (int i = 0; i < 5; i++) {
            double r = (sred[i] + sred[5 + i] + sred[10 + i] + sred[15 + i]) / (double)B;
            out[i] = (float)r;
            tot += r;
        }
        out[5] = (float)tot;
    }
}

extern "C" void kernel_launch(void* const* d_in, const int* in_sizes, int n_in,
                              void* d_out, int out_size, void* d_ws, size_t ws_size,
                              hipStream_t stream) {
    const float* preds   = (const float*)d_in[0];
    const float* targets = (const float*)d_in[1];
    const float* anchors = (const float*)d_in[2];
    float* out = (float*)d_out;

    int B = in_sizes[0] / (NCA * CH);        // 32
    int nrec = B * NCA;                      // 259584
    int scan_blocks = nrec / RPB;            // 8112 (exact: 259584 = 8112*32)
    int np = MCHUNK * B;                     // 1024
    int ns = B * MAXGT;                      // 2048

    // ws layout: cnt | gtbox | gtinfo | partial | boxdec | confdec | cls4
    char* ws = (char*)d_ws;
    size_t off = 0;
    int*    cnt     = (int*)(ws + off);      off += 128;
    float4* gtbox   = (float4*)(ws + off);   off += (size_t)ns * sizeof(float4);
    int2*   gtinfo  = (int2*)(ws + off);     off += (size_t)ns * sizeof(int2);
    float*  partial = (float*)(ws + off);    off += (size_t)np * sizeof(float);
    off = (off + 15) & ~(size_t)15;
    float4* boxdec  = (float4*)(ws + off);   off += (size_t)nrec * sizeof(float4);
    float*  confdec = (float*)(ws + off);    off += (size_t)nrec * sizeof(float);
    off = (off + 15) & ~(size_t)15;
    float4* cls4    = (float4*)(ws + off);   off += (size_t)ns * sizeof(float4);

    k_init<<<1, 64, 0, stream>>>(cnt, B);
    k_scan<<<scan_blocks, 256, 0, stream>>>(targets, preds, anchors, cnt,
                                            gtbox, gtinfo, boxdec, confdec);
    dim3 grid(MCHUNK + CLSU, B);
    k_nc<<<grid, 256, 0, stream>>>(preds, anchors, cnt, gtbox, gtinfo,
                                   boxdec, confdec, partial, cls4);
    k_final<<<1, 256, 0, stream>>>(partial, np, cls4, ns, B, out);
}

// Round 7
// 196.506 us; speedup vs baseline: 1.0607x; 1.0607x over previous
//
#include <hip/hip_runtime.h>
#include <math.h>

#define GSZ 52
#define NA 3
#define NCLS 80
#define CH 85                    // 5 + NCLS
#define NCA (GSZ*GSZ*NA)         // 8112 cell-anchors per batch
#define MAXGT 64
#define MCHUNK 32                // noobj units per batch: 32 x 256 = 8192 >= 8112
#define CLSU 16                  // cls units per batch: 16 x 4 waves = 64 slots

// fast softplus: max(x,0) + log(1+exp(-|x|)) with HW-approx exp/log.
__device__ __forceinline__ float softplus_fast(float x) {
    return fmaxf(x, 0.0f) + __logf(1.0f + __expf(-fabsf(x)));
}

// Rare path: full record read + class scan for an obj record.
__device__ __forceinline__ void emit_gt(const float* __restrict__ tg, int glob,
                                        int* cnt, float4* __restrict__ gtbox,
                                        int2* __restrict__ gtinfo) {
    const float* r = tg + (size_t)glob * CH;
    int b    = glob / NCA;
    int nloc = glob - b * NCA;
    int cid = 0;
#pragma unroll 16
    for (int c = 0; c < NCLS; c++) if (r[5 + c] > 0.5f) cid = c;
    int pos = atomicAdd(cnt + b, 1);
    if (pos < MAXGT) {
        gtbox[b * MAXGT + pos]  = make_float4(r[0], r[1], r[2], r[3]);
        gtinfo[b * MAXGT + pos] = make_int2(nloc, cid);
    }
}

// Role-split scattered scan (best measured structure, R5).
// Scattered-sector regime: ~600K 64B lines touched once; rate capped by the
// per-CU outstanding-line limit (~45) x miss latency -> ~50us floor.
// Waves 0-1: 4 box-logit loads + decode; waves 2-3: pred-conf + target-conf
// + rare GT emission. Role is wave-uniform (no divergence).
__global__ __launch_bounds__(256) void k_scan(
    const float* __restrict__ tg, const float* __restrict__ pr,
    const float* __restrict__ anchors, int nrec, int* cnt,
    float4* __restrict__ gtbox, int2* __restrict__ gtinfo,
    float4* __restrict__ boxdec, float* __restrict__ confdec) {
    int tid = threadIdx.x;
    int rec = blockIdx.x * 128 + (tid & 127);
    if (rec >= nrec) return;

    const float* rp = pr + (size_t)rec * CH;
    if (tid < 128) {
        float r0 = rp[0], r1 = rp[1], r2 = rp[2], r3 = rp[3];
        int b    = rec / NCA;
        int n    = rec - b * NCA;
        int a    = n % NA;
        int cell = n / NA;
        int gi = cell / GSZ, gj = cell % GSZ;
        float aw = anchors[2 * a], ah = anchors[2 * a + 1];
        float sx = __builtin_amdgcn_rcpf(1.0f + __expf(-r0));
        float sy = __builtin_amdgcn_rcpf(1.0f + __expf(-r1));
        float bx = (sx + (float)gj) * 8.0f;
        float by = (sy + (float)gi) * 8.0f;
        float bw = __expf(r2) * aw;
        float bh = __expf(r3) * ah;
        boxdec[rec] = make_float4(bx, by, bw, bh);
    } else {
        float pc     = rp[4];
        float conf_t = tg[(size_t)rec * CH + 4];
        confdec[rec] = pc;
        if (conf_t > 0.0f) emit_gt(tg, rec, cnt, gtbox, gtinfo);
    }
}

// Fused noobj + cls kernel (proven structure, no device-scope sync).
__global__ __launch_bounds__(256) void k_nc(
    const float* __restrict__ pr,
    const float* __restrict__ anchors,
    const int* __restrict__ cnt,
    const float4* __restrict__ gtbox,
    const int2* __restrict__ gtinfo,
    const float4* __restrict__ boxdec,
    const float* __restrict__ confdec,
    float* __restrict__ partial,
    float4* __restrict__ cls4) {
    __shared__ float4 sbox[MAXGT];
    __shared__ int    sidx[MAXGT];
    __shared__ float  swsum[4];

    int b   = blockIdx.y;
    int tid = threadIdx.x;

    if (blockIdx.x < MCHUNK) {
        int n = blockIdx.x * 256 + tid;
        int m = min(cnt[b], MAXGT);
        if (tid < m) {
            sbox[tid] = gtbox[b * MAXGT + tid];
            sidx[tid] = gtinfo[b * MAXGT + tid].x;
        }
        __syncthreads();

        float v = 0.0f;
        if (n < NCA) {
            size_t rec = (size_t)b * NCA + n;
            float4 pb = boxdec[rec];
            float  pc = confdec[rec];
            float px0 = pb.x - pb.z * 0.5f, px1 = pb.x + pb.z * 0.5f;
            float py0 = pb.y - pb.w * 0.5f, py1 = pb.y + pb.w * 0.5f;
            float areap = pb.z * pb.w;

            float best = 0.0f;
            bool isobj = false;
            for (int k = 0; k < m; k++) {
                float4 g = sbox[k];
                isobj |= (sidx[k] == n);
                float ix = fminf(px1, g.x + g.z * 0.5f) - fmaxf(px0, g.x - g.z * 0.5f);
                float iy = fminf(py1, g.y + g.w * 0.5f) - fmaxf(py0, g.y - g.w * 0.5f);
                float inter = fmaxf(ix, 0.0f) * fmaxf(iy, 0.0f);
                float u = areap + g.z * g.w - inter + 1e-9f;
                best = fmaxf(best, inter * __builtin_amdgcn_rcpf(u));
            }
            if (!isobj && best < 0.6f) v = softplus_fast(pc);
        }

        int lane = tid & 63;
        int wv   = tid >> 6;
        for (int off = 32; off > 0; off >>= 1) v += __shfl_down(v, off);
        if (lane == 0) swsum[wv] = v;
        __syncthreads();
        if (tid == 0)
            partial[b * MCHUNK + blockIdx.x] = swsum[0] + swsum[1] + swsum[2] + swsum[3];
    } else {
        int wv   = tid >> 6;
        int lane = tid & 63;
        int slot = b * MAXGT + (blockIdx.x - MCHUNK) * 4 + wv;
        int k    = slot & (MAXGT - 1);

        float4 resv = make_float4(0.f, 0.f, 0.f, 0.f);
        int m = min(cnt[b], MAXGT);
        if (k < m) {
            float4 g  = gtbox[slot];
            int2 info = gtinfo[slot];
            int n = info.x, cid = info.y;
            size_t rec = (size_t)b * NCA + n;
            const float* cl = pr + rec * CH + 5;

            float x0 = cl[lane];
            float cls = softplus_fast(x0) - (lane == cid ? x0 : 0.0f);
            if (lane < NCLS - 64) {
                float x1 = cl[64 + lane];
                cls += softplus_fast(x1) - ((64 + lane) == cid ? x1 : 0.0f);
            }
            for (int off = 32; off > 0; off >>= 1) cls += __shfl_down(cls, off);

            if (lane == 0) {
                float4 pb = boxdec[rec];
                float  pc = confdec[rec];
                int a    = n % NA;
                int cell = n / NA;
                int gi = cell / GSZ, gj = cell % GSZ;
                float aw = anchors[2 * a], ah = anchors[2 * a + 1];

                float scale = 2.0f - (g.z * (1.0f / 416.0f)) * (g.w * (1.0f / 416.0f));
                float dx = (pb.x * 0.125f - (float)gj) - (g.x * 0.125f - (float)gj);
                float dy = (pb.y * 0.125f - (float)gi) - (g.y * 0.125f - (float)gi);
                float txty = (dx * dx + dy * dy) * scale;

                float rw = __builtin_amdgcn_rcpf(aw), rh = __builtin_amdgcn_rcpf(ah);
                float pwr = fminf(fmaxf(pb.z * rw, 1e-9f), 1e9f);
                float phr = fminf(fmaxf(pb.w * rh, 1e-9f), 1e9f);
                float twr = fminf(fmaxf(g.z  * rw, 1e-9f), 1e9f);
                float thr = fminf(fmaxf(g.w  * rh, 1e-9f), 1e9f);
                float dw = __logf(pwr) - __logf(twr);
                float dh = __logf(phr) - __logf(thr);
                float twth = (dw * dw + dh * dh) * scale;

                float obj = softplus_fast(pc) - pc;
                resv = make_float4(txty, twth, obj, cls);
            }
        }
        if (lane == 0) cls4[slot] = resv;
    }
}

__global__ void k_final(const float* __restrict__ partial, int np,
                        const float4* __restrict__ cls4, int ns,
                        int B, float* __restrict__ out) {
    __shared__ double sred[4 * 5];
    int tid = threadIdx.x;
    double acc[5] = {0, 0, 0, 0, 0};   // txty, twth, noobj, obj, cls
    for (int i = tid; i < np; i += 256) acc[2] += (double)partial[i];
    for (int i = tid; i < ns; i += 256) {
        float4 v = cls4[i];
        acc[0] += (double)v.x; acc[1] += (double)v.y;
        acc[3] += (double)v.z; acc[4] += (double)v.w;
    }
    int lane = tid & 63;
    int wv   = tid >> 6;
#pragma unroll
    for (int i = 0; i < 5; i++) {
        double v = acc[i];
        for (int off = 32; off > 0; off >>= 1) v += __shfl_down(v, off);
        if (lane == 0) sred[wv * 5 + i] = v;
    }
    __syncthreads();
    if (tid == 0) {
        double tot = 0.0;
#pragma unroll
        for (int i = 0; i < 5; i++) {
            double r = (sred[i] + sred[5 + i] + sred[10 + i] + sred[15 + i]) / (double)B;
            out[i] = (float)r;
            tot += r;
        }
        out[5] = (float)tot;
    }
}

extern "C" void kernel_launch(void* const* d_in, const int* in_sizes, int n_in,
                              void* d_out, int out_size, void* d_ws, size_t ws_size,
                              hipStream_t stream) {
    const float* preds   = (const float*)d_in[0];
    const float* targets = (const float*)d_in[1];
    const float* anchors = (const float*)d_in[2];
    float* out = (float*)d_out;

    int B = in_sizes[0] / (NCA * CH);        // 32
    int nrec = B * NCA;                      // 259584
    int scan_blocks = (nrec + 127) / 128;    // 2028
    int np = MCHUNK * B;                     // 1024
    int ns = B * MAXGT;                      // 2048

    // ws layout: cnt | gtbox | gtinfo | partial | boxdec | confdec | cls4
    char* ws = (char*)d_ws;
    size_t off = 0;
    int*    cnt     = (int*)(ws + off);      off += 128;
    float4* gtbox   = (float4*)(ws + off);   off += (size_t)ns * sizeof(float4);
    int2*   gtinfo  = (int2*)(ws + off);     off += (size_t)ns * sizeof(int2);
    float*  partial = (float*)(ws + off);    off += (size_t)np * sizeof(float);
    off = (off + 15) & ~(size_t)15;
    float4* boxdec  = (float4*)(ws + off);   off += (size_t)nrec * sizeof(float4);
    float*  confdec = (float*)(ws + off);    off += (size_t)nrec * sizeof(float);
    off = (off + 15) & ~(size_t)15;
    float4* cls4    = (float4*)(ws + off);   off += (size_t)ns * sizeof(float4);

    // cnt zeroing via async memset: one fewer kernel launch + drain than k_init.
    hipMemsetAsync(cnt, 0, 128, stream);
    k_scan<<<scan_blocks, 256, 0, stream>>>(targets, preds, anchors, nrec, cnt,
                                            gtbox, gtinfo, boxdec, confdec);
    dim3 grid(MCHUNK + CLSU, B);
    k_nc<<<grid, 256, 0, stream>>>(preds, anchors, cnt, gtbox, gtinfo,
                                   boxdec, confdec, partial, cls4);
    k_final<<<1, 256, 0, stream>>>(partial, np, cls4, ns, B, out);
}